// Round 1
// baseline (3319.143 us; speedup 1.0000x reference)
//
#include <hip/hip_runtime.h>
#include <hip/hip_bf16.h>

#define N_NODES 100000
#define EMB 256
#define HID 64
#define N_REL 5
#define N_EDGES 3200000
#define BATCH 16384

// ---------------------------------------------------------------------------
// Count edges per (dst, rel) segment
// ---------------------------------------------------------------------------
__global__ void cnt_kernel(const int* __restrict__ dst, const int* __restrict__ et,
                           int* __restrict__ cnt) {
    int i = blockIdx.x * blockDim.x + threadIdx.x;
    int stride = gridDim.x * blockDim.x;
    for (int e = i; e < N_EDGES; e += stride) {
        atomicAdd(&cnt[dst[e] * N_REL + et[e]], 1);
    }
}

__global__ void inv_kernel(const int* __restrict__ cnt, float* __restrict__ inv) {
    int i = blockIdx.x * blockDim.x + threadIdx.x;
    if (i < N_NODES * N_REL) {
        inv[i] = 1.0f / fmaxf((float)cnt[i], 1.0f);
    }
}

// ---------------------------------------------------------------------------
// Dense transform: out[n, 0:64] = x[n, 0:IN] @ W[IN, 64]  (+ agg + bias, relu)
// Block: 256 threads = 16 nodes x 16 output-groups (4 outputs each, float4).
// W staged in LDS (IN*64*4 bytes; 64KB for IN=256).
// ---------------------------------------------------------------------------
template <int IN, bool RELU, bool FUSE>
__global__ void gemm_kernel(const float* __restrict__ x, const float* __restrict__ W,
                            const float* __restrict__ agg, const float* __restrict__ bias,
                            float* __restrict__ out) {
    __shared__ float Wl[IN * 64];
    // stage W cooperatively, vectorized
    for (int j = threadIdx.x; j < IN * 16; j += 256) {
        ((float4*)Wl)[j] = ((const float4*)W)[j];
    }
    __syncthreads();

    const int og = threadIdx.x & 15;   // output group: outputs og*4 .. og*4+3
    const int ln = threadIdx.x >> 4;   // local node 0..15
    const int n  = blockIdx.x * 16 + ln;
    if (n >= N_NODES) return;

    const float* xr = x + (size_t)n * IN;
    float4 acc = make_float4(0.f, 0.f, 0.f, 0.f);
    for (int i = 0; i < IN; i += 4) {
        float4 xv = *(const float4*)(xr + i);
        const float* xs = &xv.x;
#pragma unroll
        for (int j = 0; j < 4; ++j) {
            float4 w = *(const float4*)(&Wl[(i + j) * 64 + og * 4]);
            float v = xs[j];
            acc.x += v * w.x;
            acc.y += v * w.y;
            acc.z += v * w.z;
            acc.w += v * w.w;
        }
    }
    size_t o = (size_t)n * 64 + og * 4;
    if (FUSE) {
        acc.x += agg[o + 0] + bias[og * 4 + 0];
        acc.y += agg[o + 1] + bias[og * 4 + 1];
        acc.z += agg[o + 2] + bias[og * 4 + 2];
        acc.w += agg[o + 3] + bias[og * 4 + 3];
    }
    if (RELU) {
        acc.x = fmaxf(acc.x, 0.f);
        acc.y = fmaxf(acc.y, 0.f);
        acc.z = fmaxf(acc.z, 0.f);
        acc.w = fmaxf(acc.w, 0.f);
    }
    *(float4*)(out + o) = acc;
}

// ---------------------------------------------------------------------------
// Scatter messages of relation `rel`: agg[dst] += h[src] * inv[dst*R+rel]
// Each wave scans 64 edges at a time (coalesced etype read + ballot), then
// processes matching edges wave-wide (lane = feature index 0..63).
// ---------------------------------------------------------------------------
__global__ void scatter_kernel(const int* __restrict__ src, const int* __restrict__ dst,
                               const int* __restrict__ et, const float* __restrict__ h,
                               const float* __restrict__ inv, float* __restrict__ agg,
                               int rel) {
    const int lane = threadIdx.x & 63;
    const int wid  = (blockIdx.x * blockDim.x + threadIdx.x) >> 6;
    const int nw   = (gridDim.x * blockDim.x) >> 6;

    for (long base = (long)wid * 64; base < N_EDGES; base += (long)nw * 64) {
        int e = (int)base + lane;
        int myet = (e < N_EDGES) ? et[e] : -1;
        unsigned long long mask = __ballot(myet == rel);
        while (mask) {
            int bit = __ffsll((long long)mask) - 1;
            mask &= mask - 1;
            int ee = (int)base + bit;
            int s = src[ee];   // broadcast (uniform address)
            int d = dst[ee];
            float w = inv[d * N_REL + rel];
            float v = h[(size_t)s * 64 + lane] * w;
            atomicAdd(&agg[(size_t)d * 64 + lane], v);
        }
    }
}

// ---------------------------------------------------------------------------
// Merge MLP + BCE/accuracy. One wave per (sample, side); lane = hidden unit.
// ---------------------------------------------------------------------------
__global__ void loss_kernel(const float* __restrict__ nodes, const int* __restrict__ bill,
                            const int* __restrict__ u1, const int* __restrict__ u2,
                            const float* __restrict__ w1, const float* __restrict__ b1,
                            const float* __restrict__ w2, const float* __restrict__ b2,
                            float* __restrict__ out) {
    const int gw   = (blockIdx.x * blockDim.x + threadIdx.x) >> 6;
    const int lane = threadIdx.x & 63;
    if (gw >= 2 * BATCH) return;
    const int s    = gw & (BATCH - 1);
    const int side = gw >> 14;  // 0 = pos (u1), 1 = neg (u2)

    const float* xb = nodes + (size_t)bill[s] * 64;
    const float* xu = nodes + (size_t)(side ? u2[s] : u1[s]) * 64;

    float hsum = b1[lane];
    for (int i = 0; i < 64; ++i) hsum += xb[i] * w1[i * 64 + lane];
    for (int i = 0; i < 64; ++i) hsum += xu[i] * w1[(64 + i) * 64 + lane];
    hsum = fmaxf(hsum, 0.f);
    float p = hsum * w2[lane];
#pragma unroll
    for (int off = 32; off > 0; off >>= 1) p += __shfl_down(p, off);

    if (lane == 0) {
        float z = p + b2[0];
        float t = side ? 0.f : 1.f;
        float bce = fmaxf(z, 0.f) - z * t + log1pf(expf(-fabsf(z)));
        float pred = (z > 0.f) ? 1.f : 0.f;
        float corr = (pred == t) ? 1.f : 0.f;
        const float scale = 1.f / (2.f * BATCH);
        atomicAdd(&out[0], bce * scale);
        atomicAdd(&out[1], corr * scale);
    }
}

// ---------------------------------------------------------------------------
extern "C" void kernel_launch(void* const* d_in, const int* in_sizes, int n_in,
                              void* d_out, int out_size, void* d_ws, size_t ws_size,
                              hipStream_t stream) {
    const int*   bill  = (const int*)d_in[0];
    const int*   u1    = (const int*)d_in[1];
    const int*   u2    = (const int*)d_in[2];
    const int*   ei    = (const int*)d_in[3];
    const int*   et    = (const int*)d_in[4];
    const float* uf    = (const float*)d_in[5];
    const float* W1    = (const float*)d_in[6];
    const float* root1 = (const float*)d_in[7];
    const float* b1    = (const float*)d_in[8];
    const float* W2    = (const float*)d_in[9];
    const float* root2 = (const float*)d_in[10];
    const float* b2    = (const float*)d_in[11];
    const float* m1w   = (const float*)d_in[12];
    const float* m1b   = (const float*)d_in[13];
    const float* m2w   = (const float*)d_in[14];
    const float* m2b   = (const float*)d_in[15];
    float* out = (float*)d_out;

    const size_t NH = (size_t)N_NODES * 64 * sizeof(float);        // 25,600,000 B
    const size_t NRB = (size_t)N_NODES * N_REL * sizeof(int);      //  2,000,000 B
    char* ws = (char*)d_ws;
    float* agg   = (float*)(ws);
    float* hbuf  = (float*)(ws + NH);
    float* x1    = (float*)(ws + 2 * NH);
    float* nodes = (float*)(ws + 3 * NH);
    int*   cnt   = (int*)  (ws + 4 * NH);
    float* inv   = (float*)(ws + 4 * NH + NRB);
    if (ws_size < 4 * NH + 2 * NRB) return;  // workspace too small: fail visibly

    const int* src = ei;
    const int* dst = ei + N_EDGES;

    hipMemsetAsync(cnt, 0, NRB, stream);
    hipMemsetAsync(agg, 0, NH, stream);
    hipMemsetAsync(d_out, 0, 2 * sizeof(float), stream);

    cnt_kernel<<<2048, 256, 0, stream>>>(dst, et, cnt);
    inv_kernel<<<(N_NODES * N_REL + 255) / 256, 256, 0, stream>>>(cnt, inv);

    // ---- Layer 1: x1 = relu(sum_r mean_r(uf @ W1_r) + uf @ root1 + b1)
    for (int r = 0; r < N_REL; ++r) {
        gemm_kernel<EMB, false, false><<<N_NODES / 16 + 1, 256, 0, stream>>>(
            uf, W1 + (size_t)r * EMB * HID, nullptr, nullptr, hbuf);
        scatter_kernel<<<2048, 256, 0, stream>>>(src, dst, et, hbuf, inv, agg, r);
    }
    gemm_kernel<EMB, true, true><<<N_NODES / 16 + 1, 256, 0, stream>>>(
        uf, root1, agg, b1, x1);

    // ---- Layer 2: nodes = sum_r mean_r(x1 @ W2_r) + x1 @ root2 + b2
    hipMemsetAsync(agg, 0, NH, stream);
    for (int r = 0; r < N_REL; ++r) {
        gemm_kernel<HID, false, false><<<N_NODES / 16 + 1, 256, 0, stream>>>(
            x1, W2 + (size_t)r * HID * HID, nullptr, nullptr, hbuf);
        scatter_kernel<<<2048, 256, 0, stream>>>(src, dst, et, hbuf, inv, agg, r);
    }
    gemm_kernel<HID, false, true><<<N_NODES / 16 + 1, 256, 0, stream>>>(
        x1, root2, agg, b2, nodes);

    // ---- Merge MLP + BCE + accuracy
    loss_kernel<<<(2 * BATCH * 64) / 256, 256, 0, stream>>>(
        nodes, bill, u1, u2, m1w, m1b, m2w, m2b, out);
}

// Round 2
// 2542.706 us; speedup vs baseline: 1.3054x; 1.3054x over previous
//
#include <hip/hip_runtime.h>
#include <hip/hip_bf16.h>

#define N_NODES 100000
#define EMB 256
#define HID 64
#define N_REL 5
#define N_EDGES 3200000
#define BATCH 16384

// ---------------------------------------------------------------------------
// Count edges per (dst, rel) segment
// ---------------------------------------------------------------------------
__global__ void cnt_kernel(const int* __restrict__ dst, const int* __restrict__ et,
                           int* __restrict__ cnt) {
    int i = blockIdx.x * blockDim.x + threadIdx.x;
    int stride = gridDim.x * blockDim.x;
    for (int e = i; e < N_EDGES; e += stride) {
        atomicAdd(&cnt[dst[e] * N_REL + et[e]], 1);
    }
}

__global__ void inv_kernel(const int* __restrict__ cnt, float* __restrict__ inv) {
    int i = blockIdx.x * blockDim.x + threadIdx.x;
    if (i < N_NODES * N_REL) {
        inv[i] = 1.0f / fmaxf((float)cnt[i], 1.0f);
    }
}

// ---------------------------------------------------------------------------
// Dense transform: out[n, 0:64] = x[n, 0:IN] @ W[IN, 64]  (+ agg + bias, relu)
// Block: 256 threads = 16 nodes x 16 output-groups (4 outputs each, float4).
// W staged in LDS (IN*64*4 bytes; 64KB for IN=256).
// ---------------------------------------------------------------------------
template <int IN, bool RELU, bool FUSE>
__global__ void gemm_kernel(const float* __restrict__ x, const float* __restrict__ W,
                            const float* __restrict__ agg, const float* __restrict__ bias,
                            float* __restrict__ out) {
    __shared__ float Wl[IN * 64];
    for (int j = threadIdx.x; j < IN * 16; j += 256) {
        ((float4*)Wl)[j] = ((const float4*)W)[j];
    }
    __syncthreads();

    const int og = threadIdx.x & 15;   // output group: outputs og*4 .. og*4+3
    const int ln = threadIdx.x >> 4;   // local node 0..15
    const int n  = blockIdx.x * 16 + ln;
    if (n >= N_NODES) return;

    const float* xr = x + (size_t)n * IN;
    float4 acc = make_float4(0.f, 0.f, 0.f, 0.f);
    for (int i = 0; i < IN; i += 4) {
        float4 xv = *(const float4*)(xr + i);
        const float* xs = &xv.x;
#pragma unroll
        for (int j = 0; j < 4; ++j) {
            float4 w = *(const float4*)(&Wl[(i + j) * 64 + og * 4]);
            float v = xs[j];
            acc.x += v * w.x;
            acc.y += v * w.y;
            acc.z += v * w.z;
            acc.w += v * w.w;
        }
    }
    size_t o = (size_t)n * 64 + og * 4;
    if (FUSE) {
        acc.x += agg[o + 0] + bias[og * 4 + 0];
        acc.y += agg[o + 1] + bias[og * 4 + 1];
        acc.z += agg[o + 2] + bias[og * 4 + 2];
        acc.w += agg[o + 3] + bias[og * 4 + 3];
    }
    if (RELU) {
        acc.x = fmaxf(acc.x, 0.f);
        acc.y = fmaxf(acc.y, 0.f);
        acc.z = fmaxf(acc.z, 0.f);
        acc.w = fmaxf(acc.w, 0.f);
    }
    *(float4*)(out + o) = acc;
}

// ---------------------------------------------------------------------------
// Scatter messages of relation `rel`: agg[dst] += h[src] * inv[dst*R+rel]
// ---------------------------------------------------------------------------
__global__ void scatter_kernel(const int* __restrict__ src, const int* __restrict__ dst,
                               const int* __restrict__ et, const float* __restrict__ h,
                               const float* __restrict__ inv, float* __restrict__ agg,
                               int rel) {
    const int lane = threadIdx.x & 63;
    const int wid  = (blockIdx.x * blockDim.x + threadIdx.x) >> 6;
    const int nw   = (gridDim.x * blockDim.x) >> 6;

    for (long base = (long)wid * 64; base < N_EDGES; base += (long)nw * 64) {
        int e = (int)base + lane;
        int myet = (e < N_EDGES) ? et[e] : -1;
        unsigned long long mask = __ballot(myet == rel);
        while (mask) {
            int bit = __ffsll((long long)mask) - 1;
            mask &= mask - 1;
            int ee = (int)base + bit;
            int s = src[ee];   // broadcast (uniform address)
            int d = dst[ee];
            float w = inv[d * N_REL + rel];
            float v = h[(size_t)s * 64 + lane] * w;
            atomicAdd(&agg[(size_t)d * 64 + lane], v);
        }
    }
}

// ---------------------------------------------------------------------------
// Merge MLP + BCE/accuracy. Grid-strided waves; lane = hidden unit.
// Pos/neg fused per sample (bill half of hidden layer shared).
// Per-wave register accumulation -> LDS block reduce -> 2 atomics per block.
// ---------------------------------------------------------------------------
__global__ __launch_bounds__(256) void loss_kernel(
        const float* __restrict__ nodes, const int* __restrict__ bill,
        const int* __restrict__ u1, const int* __restrict__ u2,
        const float* __restrict__ w1, const float* __restrict__ b1,
        const float* __restrict__ w2, const float* __restrict__ b2,
        float* __restrict__ out) {
    __shared__ float Wl[128 * 64];   // 32 KB: full mfc1 weight
    __shared__ float red[2][4];
    for (int j = threadIdx.x; j < 128 * 16; j += 256) {
        ((float4*)Wl)[j] = ((const float4*)w1)[j];
    }
    __syncthreads();

    const int lane = threadIdx.x & 63;
    const int wv   = threadIdx.x >> 6;          // wave in block (0..3)
    const int gw   = blockIdx.x * 4 + wv;       // global wave
    const int nw   = gridDim.x * 4;

    const float bias1 = b1[lane];
    const float w2l   = w2[lane];
    const float bias2 = b2[0];

    float bce_acc = 0.f, corr_acc = 0.f;
    for (int s = gw; s < BATCH; s += nw) {
        const float* xb  = nodes + (size_t)bill[s] * 64;
        const float* xu1 = nodes + (size_t)u1[s] * 64;
        const float* xu2 = nodes + (size_t)u2[s] * 64;
        float hb = bias1, h1 = 0.f, h2 = 0.f;
#pragma unroll 8
        for (int i = 0; i < 64; ++i) {
            float wb = Wl[i * 64 + lane];
            float wu = Wl[(64 + i) * 64 + lane];
            hb += xb[i] * wb;
            h1 += xu1[i] * wu;
            h2 += xu2[i] * wu;
        }
        float p1 = fmaxf(hb + h1, 0.f) * w2l;
        float p2 = fmaxf(hb + h2, 0.f) * w2l;
#pragma unroll
        for (int off = 32; off > 0; off >>= 1) {
            p1 += __shfl_down(p1, off);
            p2 += __shfl_down(p2, off);
        }
        if (lane == 0) {
            float z1 = p1 + bias2;   // target 1
            float z2 = p2 + bias2;   // target 0
            bce_acc += fmaxf(z1, 0.f) - z1 + log1pf(expf(-fabsf(z1)));
            bce_acc += fmaxf(z2, 0.f)      + log1pf(expf(-fabsf(z2)));
            corr_acc += (z1 > 0.f) ? 1.f : 0.f;
            corr_acc += (z2 > 0.f) ? 0.f : 1.f;
        }
    }
    if (lane == 0) { red[0][wv] = bce_acc; red[1][wv] = corr_acc; }
    __syncthreads();
    if (threadIdx.x == 0) {
        const float scale = 1.f / (2.f * BATCH);
        float b = red[0][0] + red[0][1] + red[0][2] + red[0][3];
        float c = red[1][0] + red[1][1] + red[1][2] + red[1][3];
        atomicAdd(&out[0], b * scale);
        atomicAdd(&out[1], c * scale);
    }
}

// ---------------------------------------------------------------------------
extern "C" void kernel_launch(void* const* d_in, const int* in_sizes, int n_in,
                              void* d_out, int out_size, void* d_ws, size_t ws_size,
                              hipStream_t stream) {
    const int*   bill  = (const int*)d_in[0];
    const int*   u1    = (const int*)d_in[1];
    const int*   u2    = (const int*)d_in[2];
    const int*   ei    = (const int*)d_in[3];
    const int*   et    = (const int*)d_in[4];
    const float* uf    = (const float*)d_in[5];
    const float* W1    = (const float*)d_in[6];
    const float* root1 = (const float*)d_in[7];
    const float* b1    = (const float*)d_in[8];
    const float* W2    = (const float*)d_in[9];
    const float* root2 = (const float*)d_in[10];
    const float* b2    = (const float*)d_in[11];
    const float* m1w   = (const float*)d_in[12];
    const float* m1b   = (const float*)d_in[13];
    const float* m2w   = (const float*)d_in[14];
    const float* m2b   = (const float*)d_in[15];
    float* out = (float*)d_out;

    const size_t NH  = (size_t)N_NODES * 64 * sizeof(float);      // 25,600,000 B
    const size_t NRB = (size_t)N_NODES * N_REL * sizeof(int);     //  2,000,000 B
    char* ws = (char*)d_ws;
    float* agg   = (float*)(ws);
    float* hbuf  = (float*)(ws + NH);
    float* x1    = (float*)(ws + 2 * NH);
    float* nodes = (float*)(ws + 3 * NH);
    int*   cnt   = (int*)  (ws + 4 * NH);
    float* inv   = (float*)(ws + 4 * NH + NRB);
    if (ws_size < 4 * NH + 2 * NRB) return;  // workspace too small: fail visibly

    const int* src = ei;
    const int* dst = ei + N_EDGES;

    hipMemsetAsync(cnt, 0, NRB, stream);
    hipMemsetAsync(agg, 0, NH, stream);
    hipMemsetAsync(d_out, 0, 2 * sizeof(float), stream);

    cnt_kernel<<<2048, 256, 0, stream>>>(dst, et, cnt);
    inv_kernel<<<(N_NODES * N_REL + 255) / 256, 256, 0, stream>>>(cnt, inv);

    // ---- Layer 1: x1 = relu(sum_r mean_r(uf @ W1_r) + uf @ root1 + b1)
    for (int r = 0; r < N_REL; ++r) {
        gemm_kernel<EMB, false, false><<<N_NODES / 16 + 1, 256, 0, stream>>>(
            uf, W1 + (size_t)r * EMB * HID, nullptr, nullptr, hbuf);
        scatter_kernel<<<2048, 256, 0, stream>>>(src, dst, et, hbuf, inv, agg, r);
    }
    gemm_kernel<EMB, true, true><<<N_NODES / 16 + 1, 256, 0, stream>>>(
        uf, root1, agg, b1, x1);

    // ---- Layer 2: nodes = sum_r mean_r(x1 @ W2_r) + x1 @ root2 + b2
    hipMemsetAsync(agg, 0, NH, stream);
    for (int r = 0; r < N_REL; ++r) {
        gemm_kernel<HID, false, false><<<N_NODES / 16 + 1, 256, 0, stream>>>(
            x1, W2 + (size_t)r * HID * HID, nullptr, nullptr, hbuf);
        scatter_kernel<<<2048, 256, 0, stream>>>(src, dst, et, hbuf, inv, agg, r);
    }
    gemm_kernel<HID, false, true><<<N_NODES / 16 + 1, 256, 0, stream>>>(
        x1, root2, agg, b2, nodes);

    // ---- Merge MLP + BCE + accuracy
    loss_kernel<<<128, 256, 0, stream>>>(
        nodes, bill, u1, u2, m1w, m1b, m2w, m2b, out);
}

// Round 3
// 1111.779 us; speedup vs baseline: 2.9854x; 2.2871x over previous
//
#include <hip/hip_runtime.h>
#include <hip/hip_bf16.h>

#define N_NODES 100000
#define EMB 256
#define HID 64
#define N_REL 5
#define N_EDGES 3200000
#define BATCH 16384
#define NSEG (N_NODES * N_REL)          // 500000
#define NSB 489                          // ceil(NSEG / 1024)

typedef unsigned short u16;

__device__ __forceinline__ float bf2f(u16 u) {
    union { float f; unsigned int i; } v;
    v.i = ((unsigned int)u) << 16;
    return v.f;
}
__device__ __forceinline__ u16 f2bf(float f) {
    union { float f; unsigned int i; } v;
    v.f = f;
    unsigned int r = v.i + 0x7fff + ((v.i >> 16) & 1);   // RNE
    return (u16)(r >> 16);
}

// ---------------------------------------------------------------------------
// Histogram of edges per (dst, rel) segment
// ---------------------------------------------------------------------------
__global__ void cnt_kernel(const int* __restrict__ dst, const int* __restrict__ et,
                           int* __restrict__ cnt) {
    int i = blockIdx.x * blockDim.x + threadIdx.x;
    int stride = gridDim.x * blockDim.x;
    for (int e = i; e < N_EDGES; e += stride)
        atomicAdd(&cnt[dst[e] * N_REL + et[e]], 1);
}

// ---------------------------------------------------------------------------
// Exclusive scan of cnt[NSEG] -> offs[NSEG], 3 passes, 1 wave per 1024 elems
// ---------------------------------------------------------------------------
__global__ void scan1(const int* __restrict__ cnt, int* __restrict__ bsum) {
    int lane = threadIdx.x;
    int base = blockIdx.x * 1024 + lane * 16;
    int s = 0;
#pragma unroll
    for (int i = 0; i < 16; ++i) {
        int idx = base + i;
        if (idx < NSEG) s += cnt[idx];
    }
#pragma unroll
    for (int off = 32; off; off >>= 1) s += __shfl_down(s, off);
    if (lane == 0) bsum[blockIdx.x] = s;
}

__global__ void scan2(int* __restrict__ bsum) {
    int lane = threadIdx.x;
    int carry = 0;
    for (int c = 0; c < NSB; c += 64) {
        int v = (c + lane < NSB) ? bsum[c + lane] : 0;
        int incl = v;
#pragma unroll
        for (int off = 1; off < 64; off <<= 1) {
            int t = __shfl_up(incl, off);
            if (lane >= off) incl += t;
        }
        if (c + lane < NSB) bsum[c + lane] = carry + (incl - v);
        carry += __shfl(incl, 63);
    }
}

__global__ void scan3(const int* __restrict__ cnt, const int* __restrict__ bsum,
                      int* __restrict__ offs) {
    int lane = threadIdx.x;
    int base = blockIdx.x * 1024 + lane * 16;
    int v[16];
    int s = 0;
#pragma unroll
    for (int i = 0; i < 16; ++i) {
        int idx = base + i;
        v[i] = (idx < NSEG) ? cnt[idx] : 0;
        s += v[i];
    }
    int incl = s;
#pragma unroll
    for (int off = 1; off < 64; off <<= 1) {
        int t = __shfl_up(incl, off);
        if (lane >= off) incl += t;
    }
    int run = (incl - s) + bsum[blockIdx.x];
#pragma unroll
    for (int i = 0; i < 16; ++i) {
        int idx = base + i;
        if (idx < NSEG) offs[idx] = run;
        run += v[i];
    }
}

// ---------------------------------------------------------------------------
// Place src ids into (dst,rel)-sorted order
// ---------------------------------------------------------------------------
__global__ void place_kernel(const int* __restrict__ src, const int* __restrict__ dst,
                             const int* __restrict__ et, int* __restrict__ cursor,
                             int* __restrict__ sorted) {
    int i = blockIdx.x * blockDim.x + threadIdx.x;
    int stride = gridDim.x * blockDim.x;
    for (int e = i; e < N_EDGES; e += stride) {
        int pos = atomicAdd(&cursor[dst[e] * N_REL + et[e]], 1);
        sorted[pos] = src[e];
    }
}

// ---------------------------------------------------------------------------
// Fused transform: h[n, 0:384] = x[n, :] @ [W_0..W_4, root]  (bf16 out)
// Block: 256 thr = 64 nodes x 128 cols tile; grid (ceil(N/64), 3).
// LDS: Xl transposed [64k][64n] + Wl [64k][128c] = 48 KB.
// Thread: 4 nodes x (4+4) cols, 32 FMA per k.
// ---------------------------------------------------------------------------
template <int K, bool BF16_IN>
__global__ __launch_bounds__(256) void gemm_fused(
        const void* __restrict__ xin, const float* __restrict__ W,
        const float* __restrict__ root, u16* __restrict__ hout) {
    __shared__ float Xl[64][64];
    __shared__ float Wl[64][128];
    const int tid = threadIdx.x;
    const int n_base = blockIdx.x * 64;
    const int g = blockIdx.y;                    // col tile: slots 2g, 2g+1
    const int s0 = 2 * g, s1 = 2 * g + 1;
    const float* wb0 = (s0 < N_REL) ? (W + (size_t)s0 * K * 64) : root;
    const float* wb1 = (s1 < N_REL) ? (W + (size_t)s1 * K * 64) : root;

    const int cg = tid & 15;                     // col group
    const int ng = tid >> 4;                     // node group
    const int ns = tid >> 2;                     // staging node (0..63)
    const int kq = tid & 3;                      // staging k-quad group
    const bool nvalid = (n_base + ns) < N_NODES;

    float4 acc[4][2];
#pragma unroll
    for (int i = 0; i < 4; ++i) {
        acc[i][0] = make_float4(0.f, 0.f, 0.f, 0.f);
        acc[i][1] = make_float4(0.f, 0.f, 0.f, 0.f);
    }

    for (int k0 = 0; k0 < K; k0 += 64) {
        // stage X chunk, transposed to Xl[k][n]
#pragma unroll
        for (int j = 0; j < 4; ++j) {
            int kk = (kq + j * 4) * 4;           // 0,16,32,48 interleaved quads
            float4 v = make_float4(0.f, 0.f, 0.f, 0.f);
            if (nvalid) {
                if (BF16_IN) {
                    const u16* p = (const u16*)xin + (size_t)(n_base + ns) * K + k0 + kk;
                    ushort4 u = *(const ushort4*)p;
                    v = make_float4(bf2f(u.x), bf2f(u.y), bf2f(u.z), bf2f(u.w));
                } else {
                    v = *(const float4*)((const float*)xin + (size_t)(n_base + ns) * K + k0 + kk);
                }
            }
            Xl[kk + 0][ns] = v.x;
            Xl[kk + 1][ns] = v.y;
            Xl[kk + 2][ns] = v.z;
            Xl[kk + 3][ns] = v.w;
        }
        // stage W chunk [64][128]
#pragma unroll
        for (int j = 0; j < 8; ++j) {
            int idx = j * 256 + tid;             // 0..2047 float4s
            int row = idx >> 5;
            int c4 = idx & 31;
            const float* wb = (c4 < 16) ? wb0 : wb1;
            float4 wv = *(const float4*)(wb + (size_t)(k0 + row) * 64 + (c4 & 15) * 4);
            *(float4*)&Wl[row][c4 * 4] = wv;
        }
        __syncthreads();
#pragma unroll 8
        for (int k = 0; k < 64; ++k) {
            float4 xv = *(const float4*)&Xl[k][ng * 4];
            float4 w0 = *(const float4*)&Wl[k][cg * 4];
            float4 w1 = *(const float4*)&Wl[k][64 + cg * 4];
            const float* xs = &xv.x;
#pragma unroll
            for (int i = 0; i < 4; ++i) {
                float xi = xs[i];
                acc[i][0].x += xi * w0.x; acc[i][0].y += xi * w0.y;
                acc[i][0].z += xi * w0.z; acc[i][0].w += xi * w0.w;
                acc[i][1].x += xi * w1.x; acc[i][1].y += xi * w1.y;
                acc[i][1].z += xi * w1.z; acc[i][1].w += xi * w1.w;
            }
        }
        __syncthreads();
    }
#pragma unroll
    for (int i = 0; i < 4; ++i) {
        int n = n_base + ng * 4 + i;
        if (n < N_NODES) {
            u16* o = hout + (size_t)n * 384 + g * 128;
            ushort4 p0, p1;
            p0.x = f2bf(acc[i][0].x); p0.y = f2bf(acc[i][0].y);
            p0.z = f2bf(acc[i][0].z); p0.w = f2bf(acc[i][0].w);
            p1.x = f2bf(acc[i][1].x); p1.y = f2bf(acc[i][1].y);
            p1.z = f2bf(acc[i][1].z); p1.w = f2bf(acc[i][1].w);
            *(ushort4*)(o + cg * 4) = p0;
            *(ushort4*)(o + 64 + cg * 4) = p1;
        }
    }
}

// ---------------------------------------------------------------------------
// Aggregate: out[d] = (opt relu)( sum_r mean_seg(d,r) h[src, r*64:] + h[d,320:] + b )
// One wave per dst node; lane = feature. No atomics.
// ---------------------------------------------------------------------------
template <bool RELU>
__global__ __launch_bounds__(256) void aggregate_kernel(
        const u16* __restrict__ h, const int* __restrict__ srcs,
        const int* __restrict__ offs, const int* __restrict__ cnt,
        const float* __restrict__ bias, u16* __restrict__ out) {
    const int lane = threadIdx.x & 63;
    const int d = (blockIdx.x * blockDim.x + threadIdx.x) >> 6;
    if (d >= N_NODES) return;

    float acc = bf2f(h[(size_t)d * 384 + 5 * 64 + lane]) + bias[lane];
#pragma unroll
    for (int r = 0; r < N_REL; ++r) {
        int seg = d * N_REL + r;
        int o = offs[seg];
        int n = cnt[seg];
        if (n == 0) continue;
        float s = 0.f;
        int k = 0;
        for (; k + 4 <= n; k += 4) {
            int a0 = srcs[o + k + 0], a1 = srcs[o + k + 1];
            int a2 = srcs[o + k + 2], a3 = srcs[o + k + 3];
            float v0 = bf2f(h[(size_t)a0 * 384 + r * 64 + lane]);
            float v1 = bf2f(h[(size_t)a1 * 384 + r * 64 + lane]);
            float v2 = bf2f(h[(size_t)a2 * 384 + r * 64 + lane]);
            float v3 = bf2f(h[(size_t)a3 * 384 + r * 64 + lane]);
            s += (v0 + v1) + (v2 + v3);
        }
        for (; k < n; ++k)
            s += bf2f(h[(size_t)srcs[o + k] * 384 + r * 64 + lane]);
        acc += s / (float)n;
    }
    if (RELU) acc = fmaxf(acc, 0.f);
    out[(size_t)d * 64 + lane] = f2bf(acc);
}

// ---------------------------------------------------------------------------
// Merge MLP + BCE/accuracy (nodes in bf16)
// ---------------------------------------------------------------------------
__global__ __launch_bounds__(256) void loss_kernel(
        const u16* __restrict__ nodes, const int* __restrict__ bill,
        const int* __restrict__ u1, const int* __restrict__ u2,
        const float* __restrict__ w1, const float* __restrict__ b1,
        const float* __restrict__ w2, const float* __restrict__ b2,
        float* __restrict__ out) {
    __shared__ float Wl[128 * 64];
    __shared__ float red[2][4];
    for (int j = threadIdx.x; j < 128 * 16; j += 256)
        ((float4*)Wl)[j] = ((const float4*)w1)[j];
    __syncthreads();

    const int lane = threadIdx.x & 63;
    const int wv   = threadIdx.x >> 6;
    const int gw   = blockIdx.x * 4 + wv;
    const int nw   = gridDim.x * 4;

    const float bias1 = b1[lane];
    const float w2l   = w2[lane];
    const float bias2 = b2[0];

    float bce_acc = 0.f, corr_acc = 0.f;
    for (int s = gw; s < BATCH; s += nw) {
        const u16* xb  = nodes + (size_t)bill[s] * 64;
        const u16* xu1 = nodes + (size_t)u1[s] * 64;
        const u16* xu2 = nodes + (size_t)u2[s] * 64;
        float hb = bias1, h1 = 0.f, h2 = 0.f;
#pragma unroll 8
        for (int i = 0; i < 64; ++i) {
            float wb = Wl[i * 64 + lane];
            float wu = Wl[(64 + i) * 64 + lane];
            hb += bf2f(xb[i]) * wb;
            h1 += bf2f(xu1[i]) * wu;
            h2 += bf2f(xu2[i]) * wu;
        }
        float p1 = fmaxf(hb + h1, 0.f) * w2l;
        float p2 = fmaxf(hb + h2, 0.f) * w2l;
#pragma unroll
        for (int off = 32; off > 0; off >>= 1) {
            p1 += __shfl_down(p1, off);
            p2 += __shfl_down(p2, off);
        }
        if (lane == 0) {
            float z1 = p1 + bias2;   // target 1
            float z2 = p2 + bias2;   // target 0
            bce_acc += fmaxf(z1, 0.f) - z1 + log1pf(expf(-fabsf(z1)));
            bce_acc += fmaxf(z2, 0.f)      + log1pf(expf(-fabsf(z2)));
            corr_acc += (z1 > 0.f) ? 1.f : 0.f;
            corr_acc += (z2 > 0.f) ? 0.f : 1.f;
        }
    }
    if (lane == 0) { red[0][wv] = bce_acc; red[1][wv] = corr_acc; }
    __syncthreads();
    if (threadIdx.x == 0) {
        const float scale = 1.f / (2.f * BATCH);
        atomicAdd(&out[0], (red[0][0] + red[0][1] + red[0][2] + red[0][3]) * scale);
        atomicAdd(&out[1], (red[1][0] + red[1][1] + red[1][2] + red[1][3]) * scale);
    }
}

// ---------------------------------------------------------------------------
extern "C" void kernel_launch(void* const* d_in, const int* in_sizes, int n_in,
                              void* d_out, int out_size, void* d_ws, size_t ws_size,
                              hipStream_t stream) {
    const int*   bill  = (const int*)d_in[0];
    const int*   u1    = (const int*)d_in[1];
    const int*   u2    = (const int*)d_in[2];
    const int*   ei    = (const int*)d_in[3];
    const int*   et    = (const int*)d_in[4];
    const float* uf    = (const float*)d_in[5];
    const float* W1    = (const float*)d_in[6];
    const float* root1 = (const float*)d_in[7];
    const float* b1    = (const float*)d_in[8];
    const float* W2    = (const float*)d_in[9];
    const float* root2 = (const float*)d_in[10];
    const float* b2    = (const float*)d_in[11];
    const float* m1w   = (const float*)d_in[12];
    const float* m1b   = (const float*)d_in[13];
    const float* m2w   = (const float*)d_in[14];
    const float* m2b   = (const float*)d_in[15];
    float* out = (float*)d_out;

    // workspace layout (peak 106,400,000 B — proven available in round 1)
    char* ws = (char*)d_ws;
    u16* h_all  = (u16*)(ws);                        // 76,800,000  [N][384] bf16
    int* sorted = (int*)(ws + 76800000);             // 12,800,000
    u16* xbuf   = (u16*)(ws + 89600000);             // 12,800,000  x1 then nodes
    int* cursor = (int*)(ws + 89600000);             //  2,000,000  (alias, pre-x1)
    int* bsum   = (int*)(ws + 89600000 + 2000000);   //      4,096  (alias, pre-x1)
    int* cnt    = (int*)(ws + 102400000);            //  2,000,000
    int* offs   = (int*)(ws + 104400000);            //  2,000,000
    if (ws_size < 106400000) return;                 // fail visibly

    const int* src = ei;
    const int* dst = ei + N_EDGES;

    hipMemsetAsync(cnt, 0, NSEG * sizeof(int), stream);
    hipMemsetAsync(d_out, 0, 2 * sizeof(float), stream);

    // histogram -> scan -> placement (dst,rel)-sorted edge sources
    cnt_kernel<<<2048, 256, 0, stream>>>(dst, et, cnt);
    scan1<<<NSB, 64, 0, stream>>>(cnt, bsum);
    scan2<<<1, 64, 0, stream>>>(bsum);
    scan3<<<NSB, 64, 0, stream>>>(cnt, bsum, offs);
    hipMemcpyAsync(cursor, offs, NSEG * sizeof(int), hipMemcpyDeviceToDevice, stream);
    place_kernel<<<2048, 256, 0, stream>>>(src, dst, et, cursor, sorted);

    // ---- Layer 1
    gemm_fused<EMB, false><<<dim3(1563, 3), 256, 0, stream>>>(uf, W1, root1, h_all);
    aggregate_kernel<true><<<25000, 256, 0, stream>>>(h_all, sorted, offs, cnt, b1, xbuf);

    // ---- Layer 2
    gemm_fused<HID, true><<<dim3(1563, 3), 256, 0, stream>>>(xbuf, W2, root2, h_all);
    aggregate_kernel<false><<<25000, 256, 0, stream>>>(h_all, sorted, offs, cnt, b2, xbuf);

    // ---- Merge MLP + BCE + accuracy
    loss_kernel<<<128, 256, 0, stream>>>(xbuf, bill, u1, u2, m1w, m1b, m2w, m2b, out);
}

// Round 4
// 870.767 us; speedup vs baseline: 3.8117x; 1.2768x over previous
//
#include <hip/hip_runtime.h>
#include <hip/hip_bf16.h>

#define N_NODES 100000
#define EMB 256
#define HID 64
#define N_REL 5
#define N_EDGES 3200000
#define BATCH 16384
#define NSEG (N_NODES * N_REL)          // 500000
#define NSB 489                          // ceil(NSEG / 1024)

typedef unsigned short u16;
typedef __attribute__((ext_vector_type(4))) float f32x4;
typedef __attribute__((ext_vector_type(8))) short short8;

__device__ __forceinline__ float bf2f(u16 u) {
    union { float f; unsigned int i; } v;
    v.i = ((unsigned int)u) << 16;
    return v.f;
}
__device__ __forceinline__ u16 f2bf(float f) {
    union { float f; unsigned int i; } v;
    v.f = f;
    unsigned int r = v.i + 0x7fff + ((v.i >> 16) & 1);   // RNE
    return (u16)(r >> 16);
}

// async global->LDS, 16B per lane; LDS dest = uniform base + lane*16
__device__ __forceinline__ void gload_lds16(const void* g, void* l) {
    __builtin_amdgcn_global_load_lds(
        (const __attribute__((address_space(1))) unsigned int*)g,
        (__attribute__((address_space(3))) unsigned int*)l, 16, 0, 0);
}

// ---------------------------------------------------------------------------
// Histogram of edges per (dst, rel) segment
// ---------------------------------------------------------------------------
__global__ void cnt_kernel(const int* __restrict__ dst, const int* __restrict__ et,
                           int* __restrict__ cnt) {
    int i = blockIdx.x * blockDim.x + threadIdx.x;
    int stride = gridDim.x * blockDim.x;
    for (int e = i; e < N_EDGES; e += stride)
        atomicAdd(&cnt[dst[e] * N_REL + et[e]], 1);
}

// ---------------------------------------------------------------------------
// Exclusive scan of cnt[NSEG] -> offs[NSEG] (+sentinel), 3 passes
// ---------------------------------------------------------------------------
__global__ void scan1(const int* __restrict__ cnt, int* __restrict__ bsum) {
    int lane = threadIdx.x;
    int base = blockIdx.x * 1024 + lane * 16;
    int s = 0;
#pragma unroll
    for (int i = 0; i < 16; ++i) {
        int idx = base + i;
        if (idx < NSEG) s += cnt[idx];
    }
#pragma unroll
    for (int off = 32; off; off >>= 1) s += __shfl_down(s, off);
    if (lane == 0) bsum[blockIdx.x] = s;
}

__global__ void scan2(int* __restrict__ bsum, int* __restrict__ offs) {
    int lane = threadIdx.x;
    int carry = 0;
    for (int c = 0; c < NSB; c += 64) {
        int v = (c + lane < NSB) ? bsum[c + lane] : 0;
        int incl = v;
#pragma unroll
        for (int off = 1; off < 64; off <<= 1) {
            int t = __shfl_up(incl, off);
            if (lane >= off) incl += t;
        }
        if (c + lane < NSB) bsum[c + lane] = carry + (incl - v);
        carry += __shfl(incl, 63);
    }
    if (lane == 0) offs[NSEG] = N_EDGES;   // sentinel for offs-diff counts
}

__global__ void scan3(const int* __restrict__ cnt, const int* __restrict__ bsum,
                      int* __restrict__ offs) {
    int lane = threadIdx.x;
    int base = blockIdx.x * 1024 + lane * 16;
    int v[16];
    int s = 0;
#pragma unroll
    for (int i = 0; i < 16; ++i) {
        int idx = base + i;
        v[i] = (idx < NSEG) ? cnt[idx] : 0;
        s += v[i];
    }
    int incl = s;
#pragma unroll
    for (int off = 1; off < 64; off <<= 1) {
        int t = __shfl_up(incl, off);
        if (lane >= off) incl += t;
    }
    int run = (incl - s) + bsum[blockIdx.x];
#pragma unroll
    for (int i = 0; i < 16; ++i) {
        int idx = base + i;
        if (idx < NSEG) offs[idx] = run;
        run += v[i];
    }
}

// ---------------------------------------------------------------------------
// Place src ids into (dst,rel)-sorted order
// ---------------------------------------------------------------------------
__global__ void place_kernel(const int* __restrict__ src, const int* __restrict__ dst,
                             const int* __restrict__ et, int* __restrict__ cursor,
                             int* __restrict__ sorted) {
    int i = blockIdx.x * blockDim.x + threadIdx.x;
    int stride = gridDim.x * blockDim.x;
    for (int e = i; e < N_EDGES; e += stride) {
        int pos = atomicAdd(&cursor[dst[e] * N_REL + et[e]], 1);
        sorted[pos] = src[e];
    }
}

// ---------------------------------------------------------------------------
// Pack weights: BT[j][k] = (j<320 ? W[j>>6][k][j&63] : root[k][j&63]) as bf16
// ---------------------------------------------------------------------------
__global__ void build_bt(const float* __restrict__ W, const float* __restrict__ root,
                         int K, u16* __restrict__ BT) {
    int idx = blockIdx.x * blockDim.x + threadIdx.x;
    if (idx >= 384 * K) return;
    int j = idx / K, k = idx - j * K;
    float v = (j < 320) ? W[((j >> 6) * K + k) * 64 + (j & 63)]
                        : root[k * 64 + (j & 63)];
    BT[idx] = f2bf(v);
}

// ---------------------------------------------------------------------------
// MFMA GEMM: C[100000][384](bf16) = A[100000][K] x BT[384][K]^T
// 128x128 tile, 4 waves (2x2 of 64x64), K_STEP=64, 2-barrier loop (m97 style).
// A_F32: A is fp32, reg-staged with convert; else bf16 via global_load_lds.
// ---------------------------------------------------------------------------
template <int K, bool A_F32>
__global__ __launch_bounds__(256) void mfma_gemm(
        const void* __restrict__ Av, const u16* __restrict__ BT,
        u16* __restrict__ C) {
    __shared__ __align__(16) u16 Al[128 * 64];   // [row][k] 16 KB
    __shared__ __align__(16) u16 Bl[128 * 64];   // [col][k] 16 KB
    const int tid  = threadIdx.x;
    const int lane = tid & 63;
    const int wave = tid >> 6;
    const int m0 = blockIdx.x * 128;
    const int n0 = blockIdx.y * 128;
    const int wr = (wave >> 1) * 64;
    const int wc = (wave & 1) * 64;
    const int l15 = lane & 15;
    const int lg  = lane >> 4;       // 0..3

    f32x4 acc[4][4];
#pragma unroll
    for (int i = 0; i < 4; ++i)
#pragma unroll
        for (int j = 0; j < 4; ++j) {
            f32x4 z = {0.f, 0.f, 0.f, 0.f};
            acc[i][j] = z;
        }

    for (int k0 = 0; k0 < K; k0 += 64) {
        // ---- stage B tile [128 cols][64 k] via async DMA (4 KB per wave)
#pragma unroll
        for (int i = 0; i < 4; ++i) {
            int c = wave * 4 + i;                 // 1KB chunk id
            int row = c * 8 + (lane >> 3);
            int kk  = (lane & 7) * 8;
            gload_lds16(BT + (size_t)(n0 + row) * K + k0 + kk, &Bl[c * 512]);
        }
        // ---- stage A tile [128 rows][64 k]
        if (A_F32) {
            const float* Af = (const float*)Av;
#pragma unroll
            for (int p = 0; p < 8; ++p) {
                int f = p * 1024 + tid * 4;       // f32 elem index in tile
                int row = f >> 6;
                int col = f & 63;
                int gr = m0 + row;
                if (gr > N_NODES - 1) gr = N_NODES - 1;   // clamp (stores guarded)
                float4 v = *(const float4*)(Af + (size_t)gr * K + k0 + col);
                ushort4 o;
                o.x = f2bf(v.x); o.y = f2bf(v.y); o.z = f2bf(v.z); o.w = f2bf(v.w);
                *(ushort4*)&Al[row * 64 + col] = o;
            }
        } else {
            const u16* Ab = (const u16*)Av;       // padded/slop-readable buffer
#pragma unroll
            for (int i = 0; i < 4; ++i) {
                int c = wave * 4 + i;
                int row = c * 8 + (lane >> 3);
                int kk  = (lane & 7) * 8;
                gload_lds16(Ab + (size_t)(m0 + row) * K + k0 + kk, &Al[c * 512]);
            }
        }
        __syncthreads();   // drains vmcnt (DMA) + lgkm (ds_write), then barrier

        // ---- 32 MFMA per wave per K-step
#pragma unroll
        for (int kk = 0; kk < 64; kk += 32) {
            short8 af[4], bf[4];
#pragma unroll
            for (int f = 0; f < 4; ++f) {
                af[f] = *(const short8*)&Al[(wr + f * 16 + l15) * 64 + kk + lg * 8];
                bf[f] = *(const short8*)&Bl[(wc + f * 16 + l15) * 64 + kk + lg * 8];
            }
#pragma unroll
            for (int fm = 0; fm < 4; ++fm)
#pragma unroll
                for (int fn = 0; fn < 4; ++fn)
                    acc[fm][fn] = __builtin_amdgcn_mfma_f32_16x16x32_bf16(
                        af[fm], bf[fn], acc[fm][fn], 0, 0, 0);
        }
        __syncthreads();   // protect LDS before next stage
    }

    // ---- epilogue: C/D layout col=lane&15, row=4*(lane>>4)+reg
#pragma unroll
    for (int fm = 0; fm < 4; ++fm) {
        int rbase = m0 + wr + fm * 16 + lg * 4;
#pragma unroll
        for (int i = 0; i < 4; ++i) {
            int r = rbase + i;
            if (r < N_NODES) {
#pragma unroll
                for (int fn = 0; fn < 4; ++fn)
                    C[(size_t)r * 384 + n0 + wc + fn * 16 + l15] = f2bf(acc[fm][fn][i]);
            }
        }
    }
}

// ---------------------------------------------------------------------------
// Aggregate: out[d] = (opt relu)( sum_r mean_seg(d,r) h[src, r*64:] + h[d,320:] + b )
// One wave per dst node; lane = feature. Counts from offs diffs.
// ---------------------------------------------------------------------------
template <bool RELU>
__global__ __launch_bounds__(256) void aggregate_kernel(
        const u16* __restrict__ h, const int* __restrict__ srcs,
        const int* __restrict__ offs, const float* __restrict__ bias,
        u16* __restrict__ out) {
    const int lane = threadIdx.x & 63;
    const int d = (blockIdx.x * blockDim.x + threadIdx.x) >> 6;
    if (d >= N_NODES) return;

    float acc = bf2f(h[(size_t)d * 384 + 5 * 64 + lane]) + bias[lane];
#pragma unroll
    for (int r = 0; r < N_REL; ++r) {
        int seg = d * N_REL + r;
        int o = offs[seg];
        int n = offs[seg + 1] - o;
        if (n == 0) continue;
        float s = 0.f;
        int k = 0;
        for (; k + 4 <= n; k += 4) {
            int a0 = srcs[o + k + 0], a1 = srcs[o + k + 1];
            int a2 = srcs[o + k + 2], a3 = srcs[o + k + 3];
            float v0 = bf2f(h[(size_t)a0 * 384 + r * 64 + lane]);
            float v1 = bf2f(h[(size_t)a1 * 384 + r * 64 + lane]);
            float v2 = bf2f(h[(size_t)a2 * 384 + r * 64 + lane]);
            float v3 = bf2f(h[(size_t)a3 * 384 + r * 64 + lane]);
            s += (v0 + v1) + (v2 + v3);
        }
        for (; k < n; ++k)
            s += bf2f(h[(size_t)srcs[o + k] * 384 + r * 64 + lane]);
        acc += s / (float)n;
    }
    if (RELU) acc = fmaxf(acc, 0.f);
    out[(size_t)d * 64 + lane] = f2bf(acc);
}

// ---------------------------------------------------------------------------
// Merge MLP + BCE/accuracy (nodes in bf16)
// ---------------------------------------------------------------------------
__global__ __launch_bounds__(256) void loss_kernel(
        const u16* __restrict__ nodes, const int* __restrict__ bill,
        const int* __restrict__ u1, const int* __restrict__ u2,
        const float* __restrict__ w1, const float* __restrict__ b1,
        const float* __restrict__ w2, const float* __restrict__ b2,
        float* __restrict__ out) {
    __shared__ float Wl[128 * 64];
    __shared__ float red[2][4];
    for (int j = threadIdx.x; j < 128 * 16; j += 256)
        ((float4*)Wl)[j] = ((const float4*)w1)[j];
    __syncthreads();

    const int lane = threadIdx.x & 63;
    const int wv   = threadIdx.x >> 6;
    const int gw   = blockIdx.x * 4 + wv;
    const int nw   = gridDim.x * 4;

    const float bias1 = b1[lane];
    const float w2l   = w2[lane];
    const float bias2 = b2[0];

    float bce_acc = 0.f, corr_acc = 0.f;
    for (int s = gw; s < BATCH; s += nw) {
        const u16* xb  = nodes + (size_t)bill[s] * 64;
        const u16* xu1 = nodes + (size_t)u1[s] * 64;
        const u16* xu2 = nodes + (size_t)u2[s] * 64;
        float hb = bias1, h1 = 0.f, h2 = 0.f;
#pragma unroll 8
        for (int i = 0; i < 64; ++i) {
            float wb = Wl[i * 64 + lane];
            float wu = Wl[(64 + i) * 64 + lane];
            hb += bf2f(xb[i]) * wb;
            h1 += bf2f(xu1[i]) * wu;
            h2 += bf2f(xu2[i]) * wu;
        }
        float p1 = fmaxf(hb + h1, 0.f) * w2l;
        float p2 = fmaxf(hb + h2, 0.f) * w2l;
#pragma unroll
        for (int off = 32; off > 0; off >>= 1) {
            p1 += __shfl_down(p1, off);
            p2 += __shfl_down(p2, off);
        }
        if (lane == 0) {
            float z1 = p1 + bias2;   // target 1
            float z2 = p2 + bias2;   // target 0
            bce_acc += fmaxf(z1, 0.f) - z1 + log1pf(expf(-fabsf(z1)));
            bce_acc += fmaxf(z2, 0.f)      + log1pf(expf(-fabsf(z2)));
            corr_acc += (z1 > 0.f) ? 1.f : 0.f;
            corr_acc += (z2 > 0.f) ? 0.f : 1.f;
        }
    }
    if (lane == 0) { red[0][wv] = bce_acc; red[1][wv] = corr_acc; }
    __syncthreads();
    if (threadIdx.x == 0) {
        const float scale = 1.f / (2.f * BATCH);
        atomicAdd(&out[0], (red[0][0] + red[0][1] + red[0][2] + red[0][3]) * scale);
        atomicAdd(&out[1], (red[1][0] + red[1][1] + red[1][2] + red[1][3]) * scale);
    }
}

// ---------------------------------------------------------------------------
extern "C" void kernel_launch(void* const* d_in, const int* in_sizes, int n_in,
                              void* d_out, int out_size, void* d_ws, size_t ws_size,
                              hipStream_t stream) {
    const int*   bill  = (const int*)d_in[0];
    const int*   u1    = (const int*)d_in[1];
    const int*   u2    = (const int*)d_in[2];
    const int*   ei    = (const int*)d_in[3];
    const int*   et    = (const int*)d_in[4];
    const float* uf    = (const float*)d_in[5];
    const float* W1    = (const float*)d_in[6];
    const float* root1 = (const float*)d_in[7];
    const float* b1    = (const float*)d_in[8];
    const float* W2    = (const float*)d_in[9];
    const float* root2 = (const float*)d_in[10];
    const float* b2    = (const float*)d_in[11];
    const float* m1w   = (const float*)d_in[12];
    const float* m1b   = (const float*)d_in[13];
    const float* m2w   = (const float*)d_in[14];
    const float* m2b   = (const float*)d_in[15];
    float* out = (float*)d_out;

    // ws layout (peak < 106,400,000 B, the round-1-proven bound):
    //   0           h_all   76,800,000   [100000][384] bf16
    //  76,800,000   sorted  12,800,000
    //  89,600,000   xbuf    12,800,000   (+12,288 B read-only slop into offs: OK)
    //    alias pre-aggregate: cursor@+0 (2M), cnt@+2M (2M), bsum@+4M (4KB)
    // 102,400,000   offs     2,000,004   (NSEG+1 ints, sentinel)
    // 104,400,016   BT1        196,608   (16B aligned)
    // 104,596,624   BT2         49,152
    char* ws = (char*)d_ws;
    u16* h_all  = (u16*)(ws);
    int* sorted = (int*)(ws + 76800000);
    u16* xbuf   = (u16*)(ws + 89600000);
    int* cursor = (int*)(ws + 89600000);
    int* cnt    = (int*)(ws + 91600000);
    int* bsum   = (int*)(ws + 93600000);
    int* offs   = (int*)(ws + 102400000);
    u16* BT1    = (u16*)(ws + 104400016);
    u16* BT2    = (u16*)(ws + 104596624);
    if (ws_size < 106400000) return;  // fail visibly

    const int* src = ei;
    const int* dst = ei + N_EDGES;

    hipMemsetAsync(cnt, 0, NSEG * sizeof(int), stream);
    hipMemsetAsync(d_out, 0, 2 * sizeof(float), stream);

    // histogram -> scan -> placement (dst,rel)-sorted edge sources
    cnt_kernel<<<2048, 256, 0, stream>>>(dst, et, cnt);
    scan1<<<NSB, 64, 0, stream>>>(cnt, bsum);
    scan2<<<1, 64, 0, stream>>>(bsum, offs);
    scan3<<<NSB, 64, 0, stream>>>(cnt, bsum, offs);
    hipMemcpyAsync(cursor, offs, NSEG * sizeof(int), hipMemcpyDeviceToDevice, stream);
    place_kernel<<<2048, 256, 0, stream>>>(src, dst, et, cursor, sorted);

    // pack weights to BT (bf16, [384][K])
    build_bt<<<(384 * EMB + 255) / 256, 256, 0, stream>>>(W1, root1, EMB, BT1);
    build_bt<<<(384 * HID + 255) / 256, 256, 0, stream>>>(W2, root2, HID, BT2);

    // ---- Layer 1: h = uf @ [W1_r.., root1]  (MFMA, fp32 A reg-staged)
    mfma_gemm<EMB, true><<<dim3(782, 3), 256, 0, stream>>>(uf, BT1, h_all);
    aggregate_kernel<true><<<25000, 256, 0, stream>>>(h_all, sorted, offs, b1, xbuf);

    // ---- Layer 2: h = x1 @ [W2_r.., root2]  (MFMA, bf16 A via DMA)
    mfma_gemm<HID, false><<<dim3(782, 3), 256, 0, stream>>>(xbuf, BT2, h_all);
    aggregate_kernel<false><<<25000, 256, 0, stream>>>(h_all, sorted, offs, b2, xbuf);

    // ---- Merge MLP + BCE + accuracy
    loss_kernel<<<128, 256, 0, stream>>>(xbuf, bill, u1, u2, m1w, m1b, m2w, m2b, out);
}